// Round 3
// baseline (869.419 us; speedup 1.0000x reference)
//
#include <hip/hip_runtime.h>

#define Bd 32
#define Ld 64
#define Hd 512
#define Vd 32000

typedef __bf16 bf16_t;
typedef __bf16 bf16x8 __attribute__((ext_vector_type(8)));
typedef float  f32x4  __attribute__((ext_vector_type(4)));

// hl is stored as 4 chunks of 128 floats padded to 132: chunk base dword
// 132*g = 4g (mod 32)  => the 4 lane-groups read disjoint bank quads (the
// R2 layout had 128-float chunks: 32*g = 0 (mod 32) => 4-way conflict,
// 16.8M SQ_LDS_BANK_CONFLICT). Reads stay linear, weights stay linear.
#define HCHUNK 132
#define HIDX(e) ((((e) >> 7) * HCHUNK) + ((e) & 127))

// ---------------------------------------------------------------------------
// K_prep: blocks 0..255: A = embed[tok] @ Wih + bih + bhh (enc 0..127,
// dec 128..255) + clear exchange tags (must complete before k_rec).
// ---------------------------------------------------------------------------
__global__ void k_prep(
    const int* __restrict__ src, const int* __restrict__ tgt,
    const float* __restrict__ enc_embed, const float* __restrict__ enc_wih,
    const float* __restrict__ enc_bih, const float* __restrict__ enc_bhh,
    const float* __restrict__ dec_embed, const float* __restrict__ dec_wih,
    const float* __restrict__ dec_bih, const float* __restrict__ dec_bhh,
    float* __restrict__ Aenc, float* __restrict__ Adec,
    unsigned long long* __restrict__ encX, unsigned long long* __restrict__ decX)
{
    __shared__ float sm[16 * Hd];
    __shared__ int tokl[16];
    const int tid = threadIdx.x;
    const int bid = blockIdx.x;

    { // clear exchange tags (0xFF.. never matches a fresh tag)
        unsigned wgi = ((unsigned)bid << 8) + tid;       // 0..65535
        if (wgi < 32768) encX[wgi] = ~0ull;
        else             decX[wgi - 32768] = ~0ull;
    }
    const bool isDec = bid >= 128;
    const int rb = (isDec ? bid - 128 : bid) << 4;      // 16 rows per block
    const int*   toks = isDec ? tgt : src;
    const float* emb  = isDec ? dec_embed : enc_embed;
    const float* wih  = isDec ? dec_wih : enc_wih;
    const float* bi   = isDec ? dec_bih : enc_bih;
    const float* bh   = isDec ? dec_bhh : enc_bhh;
    float*       A    = isDec ? Adec : Aenc;
    if (tid < 16) {
        int r = rb + tid;                    // n = t*32 + b
        tokl[tid] = toks[(r & 31) * Ld + (r >> 5)];
    }
    __syncthreads();
    #pragma unroll
    for (int u = 0; u < 8; ++u) {            // stage 16 embedding rows
        int f = tid + (u << 8);              // float4 index [0,2048)
        int row = f >> 7, c4 = f & 127;
        ((float4*)sm)[f] = ((const float4*)(emb + (size_t)tokl[row] * Hd))[c4];
    }
    __syncthreads();
    const int j0 = tid, j1 = tid + 256;
    float acc0[16], acc1[16];
    #pragma unroll
    for (int r = 0; r < 16; ++r) { acc0[r] = 0.f; acc1[r] = 0.f; }
    #pragma unroll 4
    for (int k = 0; k < Hd; ++k) {
        float w0 = wih[(size_t)k * Hd + j0];
        float w1 = wih[(size_t)k * Hd + j1];
        #pragma unroll
        for (int r = 0; r < 16; ++r) {
            float x = sm[r * Hd + k];
            acc0[r] += x * w0;
            acc1[r] += x * w1;
        }
    }
    float bb0 = bi[j0] + bh[j0], bb1 = bi[j1] + bh[j1];
    #pragma unroll
    for (int r = 0; r < 16; ++r) {
        A[(size_t)(rb + r) * Hd + j0] = acc0[r] + bb0;
        A[(size_t)(rb + r) * Hd + j1] = acc1[r] + bb1;
    }
}

// ---------------------------------------------------------------------------
// K_rec: blocks 0..255: recurrence (1 chain-piece each, tagged-word sync).
// Blocks 256..4255: h2o_w transposed bf16 convert, overlapped under the
// latency-bound recurrence (rec blocks only ever wait on rec blocks; wcvt
// blocks never wait => always drainable => no deadlock regardless of
// dispatch order).
// ---------------------------------------------------------------------------
__global__ __launch_bounds__(256, 1) void k_rec(
    const float* __restrict__ enc_whh, const float* __restrict__ dec_whh,
    const float* __restrict__ Aenc, const float* __restrict__ Adec,
    unsigned long long* __restrict__ encX, unsigned long long* __restrict__ decX,
    bf16_t* __restrict__ dhsB,
    const float* __restrict__ w, bf16_t* __restrict__ wT)
{
    __shared__ float hl[2][4 * HCHUNK];
    __shared__ float ls[64][65];
    const int tid = threadIdx.x;
    const int bid = blockIdx.x;

    if (bid >= 256) {
        // --- h2o_w (512 x 32000 f32) -> wT (32000 x 512 bf16)
        const int b2 = bid - 256;                 // 0..3999
        const int v0 = (b2 % 500) << 6;
        const int k0 = (b2 / 500) << 6;
        #pragma unroll
        for (int u = 0; u < 16; ++u) {
            int f = tid + (u << 8);
            int r = f >> 6, cc = f & 63;
            ls[r][cc] = w[(size_t)(k0 + r) * Vd + v0 + cc];
        }
        __syncthreads();
        #pragma unroll
        for (int u = 0; u < 16; ++u) {
            int f = tid + (u << 8);
            int vr = f >> 6, kk = f & 63;
            wT[(size_t)(v0 + vr) * Hd + k0 + kk] = (bf16_t)ls[kk][vr];
        }
        return;
    }

    const int c = bid & 31, p = bid >> 5;
    const int q = tid >> 6, lane = tid & 63;
    const int l4 = lane & 15, g = lane >> 4;
    const int jb = p << 6;
    const int col = jb + (q << 4) + l4;      // this thread's output column
    const int hw0 = HIDX(tid), hw1 = HIDX(tid + 256);   // LDS write slots

    { // encoder
        float wE[128];
        #pragma unroll
        for (int i = 0; i < 128; ++i) wE[i] = enc_whh[(size_t)((g << 7) + i) * Hd + col];
        for (int t = 0; t < Ld; ++t) {
            const int par = (t + 1) & 1;
            float aval = (lane < 16) ? Aenc[(size_t)(t * Bd + c) * Hd + col] : 0.f;
            if (t == 0) {
                hl[par][hw0] = 0.f; hl[par][hw1] = 0.f;
            } else {
                const unsigned long long* xs = encX + (size_t)(((t - 1) & 1) * Bd + c) * Hd;
                const unsigned want = (unsigned)(t - 1);
                unsigned long long v0 = __hip_atomic_load(xs + tid,       __ATOMIC_RELAXED, __HIP_MEMORY_SCOPE_AGENT);
                unsigned long long v1 = __hip_atomic_load(xs + tid + 256, __ATOMIC_RELAXED, __HIP_MEMORY_SCOPE_AGENT);
                while ((unsigned)(v0 >> 32) != want || (unsigned)(v1 >> 32) != want) {
                    __builtin_amdgcn_s_sleep(1);
                    if ((unsigned)(v0 >> 32) != want)
                        v0 = __hip_atomic_load(xs + tid,       __ATOMIC_RELAXED, __HIP_MEMORY_SCOPE_AGENT);
                    if ((unsigned)(v1 >> 32) != want)
                        v1 = __hip_atomic_load(xs + tid + 256, __ATOMIC_RELAXED, __HIP_MEMORY_SCOPE_AGENT);
                }
                union { unsigned u; float f; } c0, c1;
                c0.u = (unsigned)v0; c1.u = (unsigned)v1;
                hl[par][hw0] = c0.f; hl[par][hw1] = c1.f;
            }
            __syncthreads();
            const float4* h4 = (const float4*)(hl[par] + g * HCHUNK);
            float acc = 0.f;
            #pragma unroll
            for (int i = 0; i < 32; ++i) {
                float4 hv = h4[i];
                acc += wE[4*i]*hv.x + wE[4*i+1]*hv.y + wE[4*i+2]*hv.z + wE[4*i+3]*hv.w;
            }
            acc += __shfl_xor(acc, 16, 64);
            acc += __shfl_xor(acc, 32, 64);
            if (lane < 16) {
                float h = tanhf(aval + acc);
                union { float f; unsigned u; } cv; cv.f = h;
                unsigned long long pv = ((unsigned long long)(unsigned)t << 32) | cv.u;
                __hip_atomic_store(encX + (size_t)((t & 1) * Bd + c) * Hd + col, pv,
                                   __ATOMIC_RELAXED, __HIP_MEMORY_SCOPE_AGENT);
            }
        }
    }
    { // decoder
        float wD[128];
        #pragma unroll
        for (int i = 0; i < 128; ++i) wD[i] = dec_whh[(size_t)((g << 7) + i) * Hd + col];
        for (int s = 0; s < Ld; ++s) {
            const int par = (s + 1) & 1;
            float aval = (lane < 16) ? Adec[(size_t)(s * Bd + c) * Hd + col] : 0.f;
            {
                const unsigned long long* xs = (s == 0)
                    ? (encX + (size_t)(((Ld - 1) & 1) * Bd + c) * Hd)  // encoder final
                    : (decX + (size_t)(((s - 1) & 1) * Bd + c) * Hd);
                const unsigned want = (s == 0) ? (unsigned)(Ld - 1) : (unsigned)(64 + s - 1);
                unsigned long long v0 = __hip_atomic_load(xs + tid,       __ATOMIC_RELAXED, __HIP_MEMORY_SCOPE_AGENT);
                unsigned long long v1 = __hip_atomic_load(xs + tid + 256, __ATOMIC_RELAXED, __HIP_MEMORY_SCOPE_AGENT);
                while ((unsigned)(v0 >> 32) != want || (unsigned)(v1 >> 32) != want) {
                    __builtin_amdgcn_s_sleep(1);
                    if ((unsigned)(v0 >> 32) != want)
                        v0 = __hip_atomic_load(xs + tid,       __ATOMIC_RELAXED, __HIP_MEMORY_SCOPE_AGENT);
                    if ((unsigned)(v1 >> 32) != want)
                        v1 = __hip_atomic_load(xs + tid + 256, __ATOMIC_RELAXED, __HIP_MEMORY_SCOPE_AGENT);
                }
                union { unsigned u; float f; } c0, c1;
                c0.u = (unsigned)v0; c1.u = (unsigned)v1;
                hl[par][hw0] = c0.f; hl[par][hw1] = c1.f;
            }
            __syncthreads();
            const float4* h4 = (const float4*)(hl[par] + g * HCHUNK);
            float acc = 0.f;
            #pragma unroll
            for (int i = 0; i < 32; ++i) {
                float4 hv = h4[i];
                acc += wD[4*i]*hv.x + wD[4*i+1]*hv.y + wD[4*i+2]*hv.z + wD[4*i+3]*hv.w;
            }
            acc += __shfl_xor(acc, 16, 64);
            acc += __shfl_xor(acc, 32, 64);
            if (lane < 16) {
                float h = tanhf(aval + acc);
                union { float f; unsigned u; } cv; cv.f = h;
                unsigned long long pv = ((unsigned long long)(unsigned)(64 + s) << 32) | cv.u;
                __hip_atomic_store(decX + (size_t)((s & 1) * Bd + c) * Hd + col, pv,
                                   __ATOMIC_RELAXED, __HIP_MEMORY_SCOPE_AGENT);
                dhsB[((size_t)c * Ld + s) * Hd + col] = (bf16_t)h;   // (b,t,k) for GEMM
            }
        }
    }
}

// ---------------------------------------------------------------------------
// K3: logits = dhsB (2048 x 512 bf16) @ wT^T + bias -> out (fp32 raw logits)
// + per-block softmax partials. 1-D grid 4000, XCD-chunked mapping so each
// XCD sees a contiguous v-tile range (L2 panel reuse). Reg-staged prefetch:
// kb+1's global loads issue before kb's MFMA (latency hides under compute).
// ---------------------------------------------------------------------------
__global__ __launch_bounds__(256, 2) void k_gemm(
    const bf16_t* __restrict__ Amat, const bf16_t* __restrict__ Bmat,
    const float* __restrict__ bias, float* __restrict__ out,
    float2* __restrict__ part2)
{
    __shared__ bf16_t At[128 * 32];
    __shared__ bf16_t Bt[128 * 32];
    __shared__ float smM[128][2];
    __shared__ float smL[128][2];
    const int tid = threadIdx.x;
    // XCD-chunked decode: 4000 = 8 xcds * 500; each xcd gets a contiguous
    // linear range => contiguous v-tile (y) range, all 16 n-tiles per y.
    const int bid = blockIdx.x;
    const int lin = (bid & 7) * 500 + (bid >> 3);
    const int n0 = (lin & 15) << 7;     // x fast: 16 n-tiles
    const int yv = lin >> 4;            // 250 v-tiles
    const int v0 = yv << 7;
    const int w = tid >> 6, lane = tid & 63;
    const int l15 = lane & 15, q8 = lane >> 4;
    const int moff = (w & 1) << 6, voff = (w >> 1) << 6;

    f32x4 acc[4][4];
    #pragma unroll
    for (int mi = 0; mi < 4; ++mi)
        #pragma unroll
        for (int vi = 0; vi < 4; ++vi)
            acc[mi][vi] = f32x4{0.f, 0.f, 0.f, 0.f};

    // staging geometry (2 chunks of 16B per thread per matrix)
    const int f0 = tid, f1 = tid + 256;
    const int row0 = f0 >> 2, sub0 = f0 & 3, sw0 = sub0 ^ (row0 & 3);
    const int row1 = f1 >> 2, sub1 = f1 & 3, sw1 = sub1 ^ (row1 & 3);
    const bf16_t* aP0 = Amat + (size_t)(n0 + row0) * Hd + (sub0 << 3);
    const bf16_t* aP1 = Amat + (size_t)(n0 + row1) * Hd + (sub1 << 3);
    const bf16_t* bP0 = Bmat + (size_t)(v0 + row0) * Hd + (sub0 << 3);
    const bf16_t* bP1 = Bmat + (size_t)(v0 + row1) * Hd + (sub1 << 3);

    uint4 pa0 = *(const uint4*)(aP0), pa1 = *(const uint4*)(aP1);
    uint4 pb0 = *(const uint4*)(bP0), pb1 = *(const uint4*)(bP1);

    for (int kb = 0; kb < 16; ++kb) {
        __syncthreads();
        *(uint4*)(At + row0 * 32 + (sw0 << 3)) = pa0;
        *(uint4*)(At + row1 * 32 + (sw1 << 3)) = pa1;
        *(uint4*)(Bt + row0 * 32 + (sw0 << 3)) = pb0;
        *(uint4*)(Bt + row1 * 32 + (sw1 << 3)) = pb1;
        __syncthreads();
        if (kb < 15) {
            int ko = (kb + 1) << 5;
            pa0 = *(const uint4*)(aP0 + ko); pa1 = *(const uint4*)(aP1 + ko);
            pb0 = *(const uint4*)(bP0 + ko); pb1 = *(const uint4*)(bP1 + ko);
        }
        bf16x8 af[4], bfr[4];
        #pragma unroll
        for (int mi = 0; mi < 4; ++mi) {
            int m = moff + (mi << 4) + l15;
            af[mi] = *(const bf16x8*)(At + m * 32 + (((q8 ^ (m & 3)) & 3) << 3));
        }
        #pragma unroll
        for (int vi = 0; vi < 4; ++vi) {
            int vv = voff + (vi << 4) + l15;
            bfr[vi] = *(const bf16x8*)(Bt + vv * 32 + (((q8 ^ (vv & 3)) & 3) << 3));
        }
        #pragma unroll
        for (int mi = 0; mi < 4; ++mi)
            #pragma unroll
            for (int vi = 0; vi < 4; ++vi)
                acc[mi][vi] = __builtin_amdgcn_mfma_f32_16x16x32_bf16(af[mi], bfr[vi], acc[mi][vi], 0, 0, 0);
    }

    float bz[4];
    #pragma unroll
    for (int vi = 0; vi < 4; ++vi) bz[vi] = bias[v0 + voff + (vi << 4) + l15];

    float rm[16], rl[16];
    #pragma unroll
    for (int k = 0; k < 16; ++k) rm[k] = -3.4e38f;
    #pragma unroll
    for (int mi = 0; mi < 4; ++mi)
        #pragma unroll
        for (int r = 0; r < 4; ++r)
            #pragma unroll
            for (int vi = 0; vi < 4; ++vi)
                rm[mi * 4 + r] = fmaxf(rm[mi * 4 + r], acc[mi][vi][r] + bz[vi]);
    #pragma unroll
    for (int mask = 1; mask < 16; mask <<= 1)
        #pragma unroll
        for (int k = 0; k < 16; ++k)
            rm[k] = fmaxf(rm[k], __shfl_xor(rm[k], mask, 64));
    #pragma unroll
    for (int k = 0; k < 16; ++k) rl[k] = 0.f;
    #pragma unroll
    for (int vi = 0; vi < 4; ++vi) {
        int col = v0 + voff + (vi << 4) + l15;
        #pragma unroll
        for (int mi = 0; mi < 4; ++mi) {
            int row = n0 + moff + (mi << 4) + (q8 << 2);
            #pragma unroll
            for (int r = 0; r < 4; ++r) {
                float z = acc[mi][vi][r] + bz[vi];
                out[(size_t)(row + r) * Vd + col] = z;
                rl[mi * 4 + r] += __expf(z - rm[mi * 4 + r]);
            }
        }
    }
    #pragma unroll
    for (int mask = 1; mask < 16; mask <<= 1)
        #pragma unroll
        for (int k = 0; k < 16; ++k)
            rl[k] += __shfl_xor(rl[k], mask, 64);

    if (l15 == 0) {
        int half = w >> 1;
        #pragma unroll
        for (int mi = 0; mi < 4; ++mi)
            #pragma unroll
            for (int r = 0; r < 4; ++r) {
                int rloc = moff + (mi << 4) + (q8 << 2) + r;
                smM[rloc][half] = rm[mi * 4 + r];
                smL[rloc][half] = rl[mi * 4 + r];
            }
    }
    __syncthreads();
    if (tid < 128) {
        float m0 = smM[tid][0], m1 = smM[tid][1];
        float l0 = smL[tid][0], l1 = smL[tid][1];
        float M = fmaxf(m0, m1);
        float L = l0 * __expf(m0 - M) + l1 * __expf(m1 - M);
        // transposed: row-major [n][yv] so k_lsub reads one contiguous burst
        part2[(size_t)(n0 + tid) * 250 + yv] = make_float2(M, L);
    }
}

// ---------------------------------------------------------------------------
// K4: fused logZ + subtract. One block per row: combine 250 partials
// (contiguous 2 KB), then one read+write pass over the row.
// ---------------------------------------------------------------------------
__global__ void k_lsub(float* __restrict__ out, const float2* __restrict__ part2)
{
    const int n = blockIdx.x, tid = threadIdx.x;
    __shared__ float smx[256], sl[256];
    float m = -3.4e38f, l = 0.f;
    if (tid < 250) {
        float2 pp = part2[(size_t)n * 250 + tid];
        m = pp.x; l = pp.y;
    }
    smx[tid] = m; sl[tid] = l;
    __syncthreads();
    for (int s2 = 128; s2 > 0; s2 >>= 1) {
        if (tid < s2) {
            float m1 = smx[tid], l1 = sl[tid];
            float m2 = smx[tid + s2], l2 = sl[tid + s2];
            float nm = fmaxf(m1, m2);
            sl[tid] = l1 * __expf(m1 - nm) + l2 * __expf(m2 - nm);
            smx[tid] = nm;
        }
        __syncthreads();
    }
    const float z = smx[0] + __logf(sl[0]);
    float4* row = (float4*)(out + (size_t)n * Vd);
    #pragma unroll 4
    for (int i = 0; i < 31; ++i) {             // 31*256 = 7936 of 8000 float4
        int idx = i * 256 + tid;
        float4 x = row[idx];
        x.x -= z; x.y -= z; x.z -= z; x.w -= z;
        row[idx] = x;
    }
    if (tid < 64) {                            // tail 64 float4
        int idx = 7936 + tid;
        float4 x = row[idx];
        x.x -= z; x.y -= z; x.z -= z; x.w -= z;
        row[idx] = x;
    }
}

// ---------------------------------------------------------------------------
extern "C" void kernel_launch(void* const* d_in, const int* in_sizes, int n_in,
                              void* d_out, int out_size, void* d_ws, size_t ws_size,
                              hipStream_t stream)
{
    const int*   src       = (const int*)d_in[0];
    const int*   tgt       = (const int*)d_in[1];
    const float* enc_embed = (const float*)d_in[2];
    const float* enc_wih   = (const float*)d_in[3];
    const float* enc_bih   = (const float*)d_in[4];
    const float* enc_whh   = (const float*)d_in[5];
    const float* enc_bhh   = (const float*)d_in[6];
    const float* dec_embed = (const float*)d_in[7];
    const float* dec_wih   = (const float*)d_in[8];
    const float* dec_bih   = (const float*)d_in[9];
    const float* dec_whh   = (const float*)d_in[10];
    const float* dec_bhh   = (const float*)d_in[11];
    const float* h2o_w     = (const float*)d_in[12];
    const float* h2o_b     = (const float*)d_in[13];
    float* out = (float*)d_out;

    char* ws = (char*)d_ws;
    float*  Aenc  = (float*)(ws);                        // 4 MB (dead after k_rec)
    float*  Adec  = (float*)(ws + ((size_t)4 << 20));    // 4 MB
    unsigned long long* encX = (unsigned long long*)(ws + ((size_t)8 << 20));               // 256 KB
    unsigned long long* decX = (unsigned long long*)(ws + ((size_t)8 << 20) + (256 << 10)); // 256 KB
    bf16_t* dhsB  = (bf16_t*)(ws + ((size_t)9 << 20));   // 2 MB
    bf16_t* wT    = (bf16_t*)(ws + ((size_t)12 << 20));  // 31.25 MB
    float2* part2 = (float2*)(ws);                       // 4 MB, reuses Aenc (dead)

    k_prep<<<256, 256, 0, stream>>>(src, tgt,
        enc_embed, enc_wih, enc_bih, enc_bhh,
        dec_embed, dec_wih, dec_bih, dec_bhh, Aenc, Adec, encX, decX);
    k_rec<<<4256, 256, 0, stream>>>(enc_whh, dec_whh, Aenc, Adec,
        encX, decX, dhsB, h2o_w, wT);
    k_gemm<<<4000, 256, 0, stream>>>(dhsB, wT, h2o_b, out, part2);
    k_lsub<<<2048, 256, 0, stream>>>(out, part2);
}

// Round 4
// 851.368 us; speedup vs baseline: 1.0212x; 1.0212x over previous
//
#include <hip/hip_runtime.h>

#define Bd 32
#define Ld 64
#define Hd 512
#define Vd 32000

typedef __bf16 bf16_t;
typedef __bf16 bf16x8 __attribute__((ext_vector_type(8)));
typedef float  f32x4  __attribute__((ext_vector_type(4)));

// hl chunks padded to 132 floats: chunk base dword 132*g = 4g (mod 32) =>
// the 4 lane-groups read disjoint bank quads (R2's unpadded layout was a
// 4-way conflict, 16.8M SQ_LDS_BANK_CONFLICT; R3 measured 0 with this).
#define HCHUNK 132
#define HIDX(e) ((((e) >> 7) * HCHUNK) + ((e) & 127))

// global->LDS direct staging, 16B per lane (m97 pattern: HW writes
// wave-uniform LDS base + lane*16; global src is per-lane).
__device__ __forceinline__ void gl_lds16(const bf16_t* g, bf16_t* l)
{
    __builtin_amdgcn_global_load_lds(
        (const __attribute__((address_space(1))) void*)(uintptr_t)(g),
        (__attribute__((address_space(3))) void*)(uint32_t)(uintptr_t)(l),
        16, 0, 0);
}

// ---------------------------------------------------------------------------
// K_prep: fused prologue (R2 structure — measured clean). Blocks 0..255:
// A = embed[tok] @ Wih + bih + bhh (enc 0..127, dec 128..255) + clear
// exchange tags. Blocks 256..4255: h2o_w transposed bf16 convert.
// NOTE: wcvt must NOT ride inside k_rec — R3 showed its HBM traffic congests
// the latency-bound tag-exchange fabric (+47 us on the chain).
// ---------------------------------------------------------------------------
__global__ void k_prep(
    const int* __restrict__ src, const int* __restrict__ tgt,
    const float* __restrict__ enc_embed, const float* __restrict__ enc_wih,
    const float* __restrict__ enc_bih, const float* __restrict__ enc_bhh,
    const float* __restrict__ dec_embed, const float* __restrict__ dec_wih,
    const float* __restrict__ dec_bih, const float* __restrict__ dec_bhh,
    float* __restrict__ Aenc, float* __restrict__ Adec,
    const float* __restrict__ w, bf16_t* __restrict__ wT,
    unsigned long long* __restrict__ encX, unsigned long long* __restrict__ decX)
{
    __shared__ __align__(16) char smraw[33024];
    const int tid = threadIdx.x;
    const int bid = blockIdx.x;

    if (bid < 256) {
        { // clear exchange tags (0xFF.. never matches a fresh tag)
            unsigned wgi = ((unsigned)bid << 8) + tid;       // 0..65535
            if (wgi < 32768) encX[wgi] = ~0ull;
            else             decX[wgi - 32768] = ~0ull;
        }
        float* sm  = (float*)smraw;                // 16*512 floats
        int*  tokl = (int*)(smraw + 32768);
        const bool isDec = bid >= 128;
        const int rb = (isDec ? bid - 128 : bid) << 4;      // 16 rows per block
        const int*   toks = isDec ? tgt : src;
        const float* emb  = isDec ? dec_embed : enc_embed;
        const float* wih  = isDec ? dec_wih : enc_wih;
        const float* bi   = isDec ? dec_bih : enc_bih;
        const float* bh   = isDec ? dec_bhh : enc_bhh;
        float*       A    = isDec ? Adec : Aenc;
        if (tid < 16) {
            int r = rb + tid;                    // n = t*32 + b
            tokl[tid] = toks[(r & 31) * Ld + (r >> 5)];
        }
        __syncthreads();
        #pragma unroll
        for (int u = 0; u < 8; ++u) {            // stage 16 embedding rows
            int f = tid + (u << 8);              // float4 index [0,2048)
            int row = f >> 7, c4 = f & 127;
            ((float4*)sm)[f] = ((const float4*)(emb + (size_t)tokl[row] * Hd))[c4];
        }
        __syncthreads();
        const int j0 = tid, j1 = tid + 256;
        float acc0[16], acc1[16];
        #pragma unroll
        for (int r = 0; r < 16; ++r) { acc0[r] = 0.f; acc1[r] = 0.f; }
        #pragma unroll 4
        for (int k = 0; k < Hd; ++k) {
            float w0 = wih[(size_t)k * Hd + j0];
            float w1 = wih[(size_t)k * Hd + j1];
            #pragma unroll
            for (int r = 0; r < 16; ++r) {
                float x = sm[r * Hd + k];
                acc0[r] += x * w0;
                acc1[r] += x * w1;
            }
        }
        float bb0 = bi[j0] + bh[j0], bb1 = bi[j1] + bh[j1];
        #pragma unroll
        for (int r = 0; r < 16; ++r) {
            A[(size_t)(rb + r) * Hd + j0] = acc0[r] + bb0;
            A[(size_t)(rb + r) * Hd + j1] = acc1[r] + bb1;
        }
    } else {
        // --- h2o_w (512 x 32000 f32) -> wT (32000 x 512 bf16)
        float (*ls)[65] = (float(*)[65])smraw;
        const int b2 = bid - 256;                 // 0..3999
        const int v0 = (b2 % 500) << 6;
        const int k0 = (b2 / 500) << 6;
        #pragma unroll
        for (int u = 0; u < 16; ++u) {
            int f = tid + (u << 8);
            int r = f >> 6, cc = f & 63;
            ls[r][cc] = w[(size_t)(k0 + r) * Vd + v0 + cc];
        }
        __syncthreads();
        #pragma unroll
        for (int u = 0; u < 16; ++u) {
            int f = tid + (u << 8);
            int vr = f >> 6, kk = f & 63;
            wT[(size_t)(v0 + vr) * Hd + k0 + kk] = (bf16_t)ls[kk][vr];
        }
    }
}

// ---------------------------------------------------------------------------
// K_rec: recurrence. 256 blocks x 256 threads (all resident). Block b:
// chain c = b&31, piece p = b>>5 owns 64 columns of Whh in VGPRs.
// Sync: data-is-its-own-flag (tagged 8B words, relaxed agent atomics).
// 1 barrier/step: wave-local shuffle reduce + parity-double-buffered hl.
// ---------------------------------------------------------------------------
__global__ __launch_bounds__(256, 1) void k_rec(
    const float* __restrict__ enc_whh, const float* __restrict__ dec_whh,
    const float* __restrict__ Aenc, const float* __restrict__ Adec,
    unsigned long long* __restrict__ encX, unsigned long long* __restrict__ decX,
    bf16_t* __restrict__ dhsB)
{
    __shared__ float hl[2][4 * HCHUNK];
    const int tid = threadIdx.x;
    const int bid = blockIdx.x;
    const int c = bid & 31, p = bid >> 5;
    const int q = tid >> 6, lane = tid & 63;
    const int l4 = lane & 15, g = lane >> 4;
    const int jb = p << 6;
    const int col = jb + (q << 4) + l4;      // this thread's output column
    const int hw0 = HIDX(tid), hw1 = HIDX(tid + 256);   // LDS write slots

    { // encoder
        float wE[128];
        #pragma unroll
        for (int i = 0; i < 128; ++i) wE[i] = enc_whh[(size_t)((g << 7) + i) * Hd + col];
        for (int t = 0; t < Ld; ++t) {
            const int par = (t + 1) & 1;
            float aval = (lane < 16) ? Aenc[(size_t)(t * Bd + c) * Hd + col] : 0.f;
            if (t == 0) {
                hl[par][hw0] = 0.f; hl[par][hw1] = 0.f;
            } else {
                const unsigned long long* xs = encX + (size_t)(((t - 1) & 1) * Bd + c) * Hd;
                const unsigned want = (unsigned)(t - 1);
                unsigned long long v0 = __hip_atomic_load(xs + tid,       __ATOMIC_RELAXED, __HIP_MEMORY_SCOPE_AGENT);
                unsigned long long v1 = __hip_atomic_load(xs + tid + 256, __ATOMIC_RELAXED, __HIP_MEMORY_SCOPE_AGENT);
                while ((unsigned)(v0 >> 32) != want || (unsigned)(v1 >> 32) != want) {
                    __builtin_amdgcn_s_sleep(1);
                    if ((unsigned)(v0 >> 32) != want)
                        v0 = __hip_atomic_load(xs + tid,       __ATOMIC_RELAXED, __HIP_MEMORY_SCOPE_AGENT);
                    if ((unsigned)(v1 >> 32) != want)
                        v1 = __hip_atomic_load(xs + tid + 256, __ATOMIC_RELAXED, __HIP_MEMORY_SCOPE_AGENT);
                }
                union { unsigned u; float f; } c0, c1;
                c0.u = (unsigned)v0; c1.u = (unsigned)v1;
                hl[par][hw0] = c0.f; hl[par][hw1] = c1.f;
            }
            __syncthreads();
            const float4* h4 = (const float4*)(hl[par] + g * HCHUNK);
            float acc = 0.f;
            #pragma unroll
            for (int i = 0; i < 32; ++i) {
                float4 hv = h4[i];
                acc += wE[4*i]*hv.x + wE[4*i+1]*hv.y + wE[4*i+2]*hv.z + wE[4*i+3]*hv.w;
            }
            acc += __shfl_xor(acc, 16, 64);
            acc += __shfl_xor(acc, 32, 64);
            if (lane < 16) {
                float h = tanhf(aval + acc);
                union { float f; unsigned u; } cv; cv.f = h;
                unsigned long long pv = ((unsigned long long)(unsigned)t << 32) | cv.u;
                __hip_atomic_store(encX + (size_t)((t & 1) * Bd + c) * Hd + col, pv,
                                   __ATOMIC_RELAXED, __HIP_MEMORY_SCOPE_AGENT);
            }
        }
    }
    { // decoder
        float wD[128];
        #pragma unroll
        for (int i = 0; i < 128; ++i) wD[i] = dec_whh[(size_t)((g << 7) + i) * Hd + col];
        for (int s = 0; s < Ld; ++s) {
            const int par = (s + 1) & 1;
            float aval = (lane < 16) ? Adec[(size_t)(s * Bd + c) * Hd + col] : 0.f;
            {
                const unsigned long long* xs = (s == 0)
                    ? (encX + (size_t)(((Ld - 1) & 1) * Bd + c) * Hd)  // encoder final
                    : (decX + (size_t)(((s - 1) & 1) * Bd + c) * Hd);
                const unsigned want = (s == 0) ? (unsigned)(Ld - 1) : (unsigned)(64 + s - 1);
                unsigned long long v0 = __hip_atomic_load(xs + tid,       __ATOMIC_RELAXED, __HIP_MEMORY_SCOPE_AGENT);
                unsigned long long v1 = __hip_atomic_load(xs + tid + 256, __ATOMIC_RELAXED, __HIP_MEMORY_SCOPE_AGENT);
                while ((unsigned)(v0 >> 32) != want || (unsigned)(v1 >> 32) != want) {
                    __builtin_amdgcn_s_sleep(1);
                    if ((unsigned)(v0 >> 32) != want)
                        v0 = __hip_atomic_load(xs + tid,       __ATOMIC_RELAXED, __HIP_MEMORY_SCOPE_AGENT);
                    if ((unsigned)(v1 >> 32) != want)
                        v1 = __hip_atomic_load(xs + tid + 256, __ATOMIC_RELAXED, __HIP_MEMORY_SCOPE_AGENT);
                }
                union { unsigned u; float f; } c0, c1;
                c0.u = (unsigned)v0; c1.u = (unsigned)v1;
                hl[par][hw0] = c0.f; hl[par][hw1] = c1.f;
            }
            __syncthreads();
            const float4* h4 = (const float4*)(hl[par] + g * HCHUNK);
            float acc = 0.f;
            #pragma unroll
            for (int i = 0; i < 32; ++i) {
                float4 hv = h4[i];
                acc += wD[4*i]*hv.x + wD[4*i+1]*hv.y + wD[4*i+2]*hv.z + wD[4*i+3]*hv.w;
            }
            acc += __shfl_xor(acc, 16, 64);
            acc += __shfl_xor(acc, 32, 64);
            if (lane < 16) {
                float h = tanhf(aval + acc);
                union { float f; unsigned u; } cv; cv.f = h;
                unsigned long long pv = ((unsigned long long)(unsigned)(64 + s) << 32) | cv.u;
                __hip_atomic_store(decX + (size_t)((s & 1) * Bd + c) * Hd + col, pv,
                                   __ATOMIC_RELAXED, __HIP_MEMORY_SCOPE_AGENT);
                dhsB[((size_t)c * Ld + s) * Hd + col] = (bf16_t)h;   // (b,t,k) for GEMM
            }
        }
    }
}

// ---------------------------------------------------------------------------
// K3: logits = dhsB (2048 x 512 bf16) @ wT^T + bias -> out (fp32 raw logits)
// + per-block softmax partials. XCD-chunked 1-D grid (contiguous v-range per
// XCD => L2 panel reuse). Staging via global_load_lds width=16 into LINEAR
// LDS (m97 pattern; gload_lds-direct > reg-staging at 128^2 per m151).
// ---------------------------------------------------------------------------
__global__ __launch_bounds__(256, 2) void k_gemm(
    const bf16_t* __restrict__ Amat, const bf16_t* __restrict__ Bmat,
    const float* __restrict__ bias, float* __restrict__ out,
    float2* __restrict__ part2)
{
    __shared__ __align__(16) bf16_t At[128 * 32];
    __shared__ __align__(16) bf16_t Bt[128 * 32];
    __shared__ float smM[128][2];
    __shared__ float smL[128][2];
    const int tid = threadIdx.x;
    const int bid = blockIdx.x;
    const int lin = (bid & 7) * 500 + (bid >> 3);   // XCD-chunked (4000 = 8*500)
    const int n0 = (lin & 15) << 7;     // 16 n-tiles (fast)
    const int yv = lin >> 4;            // 250 v-tiles
    const int v0 = yv << 7;
    const int w = tid >> 6, lane = tid & 63;
    const int l15 = lane & 15, q8 = lane >> 4;
    const int moff = (w & 1) << 6, voff = (w >> 1) << 6;

    f32x4 acc[4][4];
    #pragma unroll
    for (int mi = 0; mi < 4; ++mi)
        #pragma unroll
        for (int vi = 0; vi < 4; ++vi)
            acc[mi][vi] = f32x4{0.f, 0.f, 0.f, 0.f};

    // staging geometry: wave w covers row chunks (2w) and (2w+1); within a
    // chunk lane l -> row + l/4, col (l&3)*8. HW writes LDS at chunkbase+l*16.
    const int srow = lane >> 2;
    const int scol = (lane & 3) << 3;
    bf16_t* ldsA0 = At + ((w << 1) + 0) * 512;   // 16 rows * 32 cols
    bf16_t* ldsA1 = At + ((w << 1) + 1) * 512;
    bf16_t* ldsB0 = Bt + ((w << 1) + 0) * 512;
    bf16_t* ldsB1 = Bt + ((w << 1) + 1) * 512;
    const int r0 = ((w << 1) + 0) * 16 + srow;
    const int r1 = ((w << 1) + 1) * 16 + srow;
    const bf16_t* aS0 = Amat + (size_t)(n0 + r0) * Hd + scol;
    const bf16_t* aS1 = Amat + (size_t)(n0 + r1) * Hd + scol;
    const bf16_t* bS0 = Bmat + (size_t)(v0 + r0) * Hd + scol;
    const bf16_t* bS1 = Bmat + (size_t)(v0 + r1) * Hd + scol;

    for (int kb = 0; kb < 16; ++kb) {
        __syncthreads();                       // prev tile fully read
        const int ko = kb << 5;
        gl_lds16(aS0 + ko, ldsA0);
        gl_lds16(aS1 + ko, ldsA1);
        gl_lds16(bS0 + ko, ldsB0);
        gl_lds16(bS1 + ko, ldsB1);
        __syncthreads();                       // vmcnt drained -> LDS valid
        bf16x8 af[4], bfr[4];
        #pragma unroll
        for (int mi = 0; mi < 4; ++mi) {
            int m = moff + (mi << 4) + l15;
            af[mi] = *(const bf16x8*)(At + m * 32 + (q8 << 3));
        }
        #pragma unroll
        for (int vi = 0; vi < 4; ++vi) {
            int vv = voff + (vi << 4) + l15;
            bfr[vi] = *(const bf16x8*)(Bt + vv * 32 + (q8 << 3));
        }
        #pragma unroll
        for (int mi = 0; mi < 4; ++mi)
            #pragma unroll
            for (int vi = 0; vi < 4; ++vi)
                acc[mi][vi] = __builtin_amdgcn_mfma_f32_16x16x32_bf16(af[mi], bfr[vi], acc[mi][vi], 0, 0, 0);
    }

    float bz[4];
    #pragma unroll
    for (int vi = 0; vi < 4; ++vi) bz[vi] = bias[v0 + voff + (vi << 4) + l15];

    float rm[16], rl[16];
    #pragma unroll
    for (int k = 0; k < 16; ++k) rm[k] = -3.4e38f;
    #pragma unroll
    for (int mi = 0; mi < 4; ++mi)
        #pragma unroll
        for (int r = 0; r < 4; ++r)
            #pragma unroll
            for (int vi = 0; vi < 4; ++vi)
                rm[mi * 4 + r] = fmaxf(rm[mi * 4 + r], acc[mi][vi][r] + bz[vi]);
    #pragma unroll
    for (int mask = 1; mask < 16; mask <<= 1)
        #pragma unroll
        for (int k = 0; k < 16; ++k)
            rm[k] = fmaxf(rm[k], __shfl_xor(rm[k], mask, 64));
    #pragma unroll
    for (int k = 0; k < 16; ++k) rl[k] = 0.f;
    #pragma unroll
    for (int vi = 0; vi < 4; ++vi) {
        int col = v0 + voff + (vi << 4) + l15;
        #pragma unroll
        for (int mi = 0; mi < 4; ++mi) {
            int row = n0 + moff + (mi << 4) + (q8 << 2);
            #pragma unroll
            for (int r = 0; r < 4; ++r) {
                float z = acc[mi][vi][r] + bz[vi];
                out[(size_t)(row + r) * Vd + col] = z;
                rl[mi * 4 + r] += __expf(z - rm[mi * 4 + r]);
            }
        }
    }
    #pragma unroll
    for (int mask = 1; mask < 16; mask <<= 1)
        #pragma unroll
        for (int k = 0; k < 16; ++k)
            rl[k] += __shfl_xor(rl[k], mask, 64);

    if (l15 == 0) {
        int half = w >> 1;
        #pragma unroll
        for (int mi = 0; mi < 4; ++mi)
            #pragma unroll
            for (int r = 0; r < 4; ++r) {
                int rloc = moff + (mi << 4) + (q8 << 2) + r;
                smM[rloc][half] = rm[mi * 4 + r];
                smL[rloc][half] = rl[mi * 4 + r];
            }
    }
    __syncthreads();
    if (tid < 128) {
        float m0 = smM[tid][0], m1 = smM[tid][1];
        float l0 = smL[tid][0], l1 = smL[tid][1];
        float M = fmaxf(m0, m1);
        float L = l0 * __expf(m0 - M) + l1 * __expf(m1 - M);
        part2[(size_t)(n0 + tid) * 250 + yv] = make_float2(M, L);
    }
}

// ---------------------------------------------------------------------------
// K4: fused logZ + subtract. One block per row: combine 250 partials
// (contiguous 2 KB), then one read+write pass over the row.
// ---------------------------------------------------------------------------
__global__ void k_lsub(float* __restrict__ out, const float2* __restrict__ part2)
{
    const int n = blockIdx.x, tid = threadIdx.x;
    __shared__ float smx[256], sl[256];
    float m = -3.4e38f, l = 0.f;
    if (tid < 250) {
        float2 pp = part2[(size_t)n * 250 + tid];
        m = pp.x; l = pp.y;
    }
    smx[tid] = m; sl[tid] = l;
    __syncthreads();
    for (int s2 = 128; s2 > 0; s2 >>= 1) {
        if (tid < s2) {
            float m1 = smx[tid], l1 = sl[tid];
            float m2 = smx[tid + s2], l2 = sl[tid + s2];
            float nm = fmaxf(m1, m2);
            sl[tid] = l1 * __expf(m1 - nm) + l2 * __expf(m2 - nm);
            smx[tid] = nm;
        }
        __syncthreads();
    }
    const float z = smx[0] + __logf(sl[0]);
    float4* row = (float4*)(out + (size_t)n * Vd);
    #pragma unroll 4
    for (int i = 0; i < 31; ++i) {             // 31*256 = 7936 of 8000 float4
        int idx = i * 256 + tid;
        float4 x = row[idx];
        x.x -= z; x.y -= z; x.z -= z; x.w -= z;
        row[idx] = x;
    }
    if (tid < 64) {                            // tail 64 float4
        int idx = 7936 + tid;
        float4 x = row[idx];
        x.x -= z; x.y -= z; x.z -= z; x.w -= z;
        row[idx] = x;
    }
}

// ---------------------------------------------------------------------------
extern "C" void kernel_launch(void* const* d_in, const int* in_sizes, int n_in,
                              void* d_out, int out_size, void* d_ws, size_t ws_size,
                              hipStream_t stream)
{
    const int*   src       = (const int*)d_in[0];
    const int*   tgt       = (const int*)d_in[1];
    const float* enc_embed = (const float*)d_in[2];
    const float* enc_wih   = (const float*)d_in[3];
    const float* enc_bih   = (const float*)d_in[4];
    const float* enc_whh   = (const float*)d_in[5];
    const float* enc_bhh   = (const float*)d_in[6];
    const float* dec_embed = (const float*)d_in[7];
    const float* dec_wih   = (const float*)d_in[8];
    const float* dec_bih   = (const float*)d_in[9];
    const float* dec_whh   = (const float*)d_in[10];
    const float* dec_bhh   = (const float*)d_in[11];
    const float* h2o_w     = (const float*)d_in[12];
    const float* h2o_b     = (const float*)d_in[13];
    float* out = (float*)d_out;

    char* ws = (char*)d_ws;
    float*  Aenc  = (float*)(ws);                        // 4 MB (dead after k_rec)
    float*  Adec  = (float*)(ws + ((size_t)4 << 20));    // 4 MB
    unsigned long long* encX = (unsigned long long*)(ws + ((size_t)8 << 20));               // 256 KB
    unsigned long long* decX = (unsigned long long*)(ws + ((size_t)8 << 20) + (256 << 10)); // 256 KB
    bf16_t* dhsB  = (bf16_t*)(ws + ((size_t)9 << 20));   // 2 MB
    bf16_t* wT    = (bf16_t*)(ws + ((size_t)12 << 20));  // 31.25 MB
    float2* part2 = (float2*)(ws);                       // 4 MB, reuses Aenc (dead)

    k_prep<<<4256, 256, 0, stream>>>(src, tgt,
        enc_embed, enc_wih, enc_bih, enc_bhh,
        dec_embed, dec_wih, dec_bih, dec_bhh, Aenc, Adec,
        h2o_w, wT, encX, decX);
    k_rec<<<256, 256, 0, stream>>>(enc_whh, dec_whh, Aenc, Adec,
        encX, decX, dhsB);
    k_gemm<<<4000, 256, 0, stream>>>(dhsB, wT, h2o_b, out, part2);
    k_lsub<<<2048, 256, 0, stream>>>(out, part2);
}

// Round 5
// 835.520 us; speedup vs baseline: 1.0406x; 1.0190x over previous
//
#include <hip/hip_runtime.h>

#define Bd 32
#define Ld 64
#define Hd 512
#define Vd 32000

typedef __bf16 bf16_t;
typedef __bf16 bf16x8 __attribute__((ext_vector_type(8)));
typedef float  f32x4  __attribute__((ext_vector_type(4)));

// hl chunks padded to 132 floats: chunk base dword 132*g = 4g (mod 32) =>
// the 4 lane-groups read disjoint bank quads (R3/R4 measured 0 conflicts).
#define HCHUNK 132
#define HIDX(e) ((((e) >> 7) * HCHUNK) + ((e) & 127))

// fast tanh: (e^2x - 1) / (e^2x + 1), saturates correctly at +-1.
__device__ __forceinline__ float ftanh(float x)
{
    float e = __expf(2.f * x);
    return 1.f - 2.f / (e + 1.f);
}

// ---------------------------------------------------------------------------
// K_prep: fused prologue. Blocks 0..255: A = embed[tok] @ Wih + bih + bhh
// (enc 0..127, dec 128..255) + clear exchange tags. Blocks 256..4255: h2o_w
// transposed bf16 convert. (wcvt must NOT ride inside k_rec — R3 showed its
// HBM traffic congests the latency-bound tag-exchange fabric.)
// ---------------------------------------------------------------------------
__global__ void k_prep(
    const int* __restrict__ src, const int* __restrict__ tgt,
    const float* __restrict__ enc_embed, const float* __restrict__ enc_wih,
    const float* __restrict__ enc_bih, const float* __restrict__ enc_bhh,
    const float* __restrict__ dec_embed, const float* __restrict__ dec_wih,
    const float* __restrict__ dec_bih, const float* __restrict__ dec_bhh,
    float* __restrict__ Aenc, float* __restrict__ Adec,
    const float* __restrict__ w, bf16_t* __restrict__ wT,
    unsigned long long* __restrict__ encX, unsigned long long* __restrict__ decX)
{
    __shared__ __align__(16) char smraw[33024];
    const int tid = threadIdx.x;
    const int bid = blockIdx.x;

    if (bid < 256) {
        { // clear exchange tags (0xFF.. never matches a fresh tag)
            unsigned wgi = ((unsigned)bid << 8) + tid;       // 0..65535
            if (wgi < 32768) encX[wgi] = ~0ull;
            else             decX[wgi - 32768] = ~0ull;
        }
        float* sm  = (float*)smraw;                // 16*512 floats
        int*  tokl = (int*)(smraw + 32768);
        const bool isDec = bid >= 128;
        const int rb = (isDec ? bid - 128 : bid) << 4;      // 16 rows per block
        const int*   toks = isDec ? tgt : src;
        const float* emb  = isDec ? dec_embed : enc_embed;
        const float* wih  = isDec ? dec_wih : enc_wih;
        const float* bi   = isDec ? dec_bih : enc_bih;
        const float* bh   = isDec ? dec_bhh : enc_bhh;
        float*       A    = isDec ? Adec : Aenc;
        if (tid < 16) {
            int r = rb + tid;                    // n = t*32 + b
            tokl[tid] = toks[(r & 31) * Ld + (r >> 5)];
        }
        __syncthreads();
        #pragma unroll
        for (int u = 0; u < 8; ++u) {            // stage 16 embedding rows
            int f = tid + (u << 8);              // float4 index [0,2048)
            int row = f >> 7, c4 = f & 127;
            ((float4*)sm)[f] = ((const float4*)(emb + (size_t)tokl[row] * Hd))[c4];
        }
        __syncthreads();
        const int j0 = tid, j1 = tid + 256;
        float acc0[16], acc1[16];
        #pragma unroll
        for (int r = 0; r < 16; ++r) { acc0[r] = 0.f; acc1[r] = 0.f; }
        #pragma unroll 4
        for (int k = 0; k < Hd; ++k) {
            float w0 = wih[(size_t)k * Hd + j0];
            float w1 = wih[(size_t)k * Hd + j1];
            #pragma unroll
            for (int r = 0; r < 16; ++r) {
                float x = sm[r * Hd + k];
                acc0[r] += x * w0;
                acc1[r] += x * w1;
            }
        }
        float bb0 = bi[j0] + bh[j0], bb1 = bi[j1] + bh[j1];
        #pragma unroll
        for (int r = 0; r < 16; ++r) {
            A[(size_t)(rb + r) * Hd + j0] = acc0[r] + bb0;
            A[(size_t)(rb + r) * Hd + j1] = acc1[r] + bb1;
        }
    } else {
        // --- h2o_w (512 x 32000 f32) -> wT (32000 x 512 bf16)
        float (*ls)[65] = (float(*)[65])smraw;
        const int b2 = bid - 256;                 // 0..3999
        const int v0 = (b2 % 500) << 6;
        const int k0 = (b2 / 500) << 6;
        #pragma unroll
        for (int u = 0; u < 16; ++u) {
            int f = tid + (u << 8);
            int r = f >> 6, cc = f & 63;
            ls[r][cc] = w[(size_t)(k0 + r) * Vd + v0 + cc];
        }
        __syncthreads();
        #pragma unroll
        for (int u = 0; u < 16; ++u) {
            int f = tid + (u << 8);
            int vr = f >> 6, kk = f & 63;
            wT[(size_t)(v0 + vr) * Hd + k0 + kk] = (bf16_t)ls[kk][vr];
        }
    }
}

// ---------------------------------------------------------------------------
// K_rec: recurrence. 256 blocks x 256 threads (all resident). Block b:
// chain c = b&31, piece p = b>>5 owns 64 columns of Whh in VGPRs.
// Sync: data-is-its-own-flag (tagged 8B words, relaxed agent atomics).
// Structure (R5): conflict-free vectorized dot + wave-shuffle reduce
// (R4), sums routed via res[64] so wave 0 alone does tanh and ONE
// coalesced 512B tagged store (R1's consolidated production — 4-wave
// scattered stores cost ~230cy/step of last-arrival stagger, R1 vs R4).
// ---------------------------------------------------------------------------
__global__ __launch_bounds__(256, 1) void k_rec(
    const float* __restrict__ enc_whh, const float* __restrict__ dec_whh,
    const float* __restrict__ Aenc, const float* __restrict__ Adec,
    unsigned long long* __restrict__ encX, unsigned long long* __restrict__ decX,
    bf16_t* __restrict__ dhsB)
{
    __shared__ float hl[2][4 * HCHUNK];
    __shared__ float res[64];
    const int tid = threadIdx.x;
    const int bid = blockIdx.x;
    const int c = bid & 31, p = bid >> 5;
    const int q = tid >> 6, lane = tid & 63;
    const int l4 = lane & 15, g = lane >> 4;
    const int jb = p << 6;
    const int col = jb + (q << 4) + l4;      // this thread's dot column
    const int hw0 = HIDX(tid), hw1 = HIDX(tid + 256);   // LDS write slots

    { // encoder
        float wE[128];
        #pragma unroll
        for (int i = 0; i < 128; ++i) wE[i] = enc_whh[(size_t)((g << 7) + i) * Hd + col];
        for (int t = 0; t < Ld; ++t) {
            const int ip = (t + 1) & 1;          // input buffer parity
            // hoisted: wave0's A value for the epilogue column jb+tid
            float aval = (tid < 64) ? Aenc[(size_t)(t * Bd + c) * Hd + jb + tid] : 0.f;
            if (t == 0) {
                hl[ip][hw0] = 0.f; hl[ip][hw1] = 0.f;
            } else {
                const unsigned long long* xs = encX + (size_t)(((t - 1) & 1) * Bd + c) * Hd;
                const unsigned want = (unsigned)(t - 1);
                unsigned long long v0 = __hip_atomic_load(xs + tid,       __ATOMIC_RELAXED, __HIP_MEMORY_SCOPE_AGENT);
                unsigned long long v1 = __hip_atomic_load(xs + tid + 256, __ATOMIC_RELAXED, __HIP_MEMORY_SCOPE_AGENT);
                while ((unsigned)(v0 >> 32) != want || (unsigned)(v1 >> 32) != want) {
                    __builtin_amdgcn_s_sleep(1);
                    if ((unsigned)(v0 >> 32) != want)
                        v0 = __hip_atomic_load(xs + tid,       __ATOMIC_RELAXED, __HIP_MEMORY_SCOPE_AGENT);
                    if ((unsigned)(v1 >> 32) != want)
                        v1 = __hip_atomic_load(xs + tid + 256, __ATOMIC_RELAXED, __HIP_MEMORY_SCOPE_AGENT);
                }
                union { unsigned u; float f; } c0, c1;
                c0.u = (unsigned)v0; c1.u = (unsigned)v1;
                hl[ip][hw0] = c0.f; hl[ip][hw1] = c1.f;
            }
            __syncthreads();                      // bar 1: hl ready
            const float4* h4 = (const float4*)(hl[ip] + g * HCHUNK);
            float acc = 0.f;
            #pragma unroll
            for (int i = 0; i < 32; ++i) {
                float4 hv = h4[i];
                acc += wE[4*i]*hv.x + wE[4*i+1]*hv.y + wE[4*i+2]*hv.z + wE[4*i+3]*hv.w;
            }
            acc += __shfl_xor(acc, 16, 64);
            acc += __shfl_xor(acc, 32, 64);
            if (lane < 16) res[(q << 4) + l4] = acc;
            __syncthreads();                      // bar 2: res ready
            if (tid < 64) {                       // wave 0: single 512B store
                float h = ftanh(aval + res[tid]);
                union { float f; unsigned u; } cv; cv.f = h;
                unsigned long long pv = ((unsigned long long)(unsigned)t << 32) | cv.u;
                __hip_atomic_store(encX + (size_t)((t & 1) * Bd + c) * Hd + jb + tid, pv,
                                   __ATOMIC_RELAXED, __HIP_MEMORY_SCOPE_AGENT);
            }
        }
    }
    { // decoder
        float wD[128];
        #pragma unroll
        for (int i = 0; i < 128; ++i) wD[i] = dec_whh[(size_t)((g << 7) + i) * Hd + col];
        for (int s = 0; s < Ld; ++s) {
            const int ip = (s + 1) & 1;
            float aval = (tid < 64) ? Adec[(size_t)(s * Bd + c) * Hd + jb + tid] : 0.f;
            {
                const unsigned long long* xs = (s == 0)
                    ? (encX + (size_t)(((Ld - 1) & 1) * Bd + c) * Hd)  // encoder final
                    : (decX + (size_t)(((s - 1) & 1) * Bd + c) * Hd);
                const unsigned want = (s == 0) ? (unsigned)(Ld - 1) : (unsigned)(64 + s - 1);
                unsigned long long v0 = __hip_atomic_load(xs + tid,       __ATOMIC_RELAXED, __HIP_MEMORY_SCOPE_AGENT);
                unsigned long long v1 = __hip_atomic_load(xs + tid + 256, __ATOMIC_RELAXED, __HIP_MEMORY_SCOPE_AGENT);
                while ((unsigned)(v0 >> 32) != want || (unsigned)(v1 >> 32) != want) {
                    __builtin_amdgcn_s_sleep(1);
                    if ((unsigned)(v0 >> 32) != want)
                        v0 = __hip_atomic_load(xs + tid,       __ATOMIC_RELAXED, __HIP_MEMORY_SCOPE_AGENT);
                    if ((unsigned)(v1 >> 32) != want)
                        v1 = __hip_atomic_load(xs + tid + 256, __ATOMIC_RELAXED, __HIP_MEMORY_SCOPE_AGENT);
                }
                union { unsigned u; float f; } c0, c1;
                c0.u = (unsigned)v0; c1.u = (unsigned)v1;
                hl[ip][hw0] = c0.f; hl[ip][hw1] = c1.f;
            }
            __syncthreads();                      // bar 1
            const float4* h4 = (const float4*)(hl[ip] + g * HCHUNK);
            float acc = 0.f;
            #pragma unroll
            for (int i = 0; i < 32; ++i) {
                float4 hv = h4[i];
                acc += wD[4*i]*hv.x + wD[4*i+1]*hv.y + wD[4*i+2]*hv.z + wD[4*i+3]*hv.w;
            }
            acc += __shfl_xor(acc, 16, 64);
            acc += __shfl_xor(acc, 32, 64);
            if (lane < 16) res[(q << 4) + l4] = acc;
            __syncthreads();                      // bar 2
            if (tid < 64) {
                float h = ftanh(aval + res[tid]);
                union { float f; unsigned u; } cv; cv.f = h;
                unsigned long long pv = ((unsigned long long)(unsigned)(64 + s) << 32) | cv.u;
                __hip_atomic_store(decX + (size_t)((s & 1) * Bd + c) * Hd + jb + tid, pv,
                                   __ATOMIC_RELAXED, __HIP_MEMORY_SCOPE_AGENT);
                dhsB[((size_t)c * Ld + s) * Hd + jb + tid] = (bf16_t)h;   // (b,t,k)
            }
        }
    }
}

// ---------------------------------------------------------------------------
// K3: logits = dhsB (2048 x 512 bf16) @ wT^T + bias -> out (fp32 raw logits)
// + per-block softmax partials. R3 version (measured best): reg-staged
// prefetch + XOR-swizzled LDS + XCD-chunked 1-D grid. (The R4 gload_lds
// linear-LDS variant read-conflicts 8-way at 64B row stride — regressed.)
// ---------------------------------------------------------------------------
__global__ __launch_bounds__(256, 2) void k_gemm(
    const bf16_t* __restrict__ Amat, const bf16_t* __restrict__ Bmat,
    const float* __restrict__ bias, float* __restrict__ out,
    float2* __restrict__ part2)
{
    __shared__ bf16_t At[128 * 32];
    __shared__ bf16_t Bt[128 * 32];
    __shared__ float smM[128][2];
    __shared__ float smL[128][2];
    const int tid = threadIdx.x;
    const int bid = blockIdx.x;
    const int lin = (bid & 7) * 500 + (bid >> 3);   // XCD-chunked (4000 = 8*500)
    const int n0 = (lin & 15) << 7;     // 16 n-tiles (fast)
    const int yv = lin >> 4;            // 250 v-tiles
    const int v0 = yv << 7;
    const int w = tid >> 6, lane = tid & 63;
    const int l15 = lane & 15, q8 = lane >> 4;
    const int moff = (w & 1) << 6, voff = (w >> 1) << 6;

    f32x4 acc[4][4];
    #pragma unroll
    for (int mi = 0; mi < 4; ++mi)
        #pragma unroll
        for (int vi = 0; vi < 4; ++vi)
            acc[mi][vi] = f32x4{0.f, 0.f, 0.f, 0.f};

    // staging geometry (2 chunks of 16B per thread per matrix)
    const int f0 = tid, f1 = tid + 256;
    const int row0 = f0 >> 2, sub0 = f0 & 3, sw0 = sub0 ^ (row0 & 3);
    const int row1 = f1 >> 2, sub1 = f1 & 3, sw1 = sub1 ^ (row1 & 3);
    const bf16_t* aP0 = Amat + (size_t)(n0 + row0) * Hd + (sub0 << 3);
    const bf16_t* aP1 = Amat + (size_t)(n0 + row1) * Hd + (sub1 << 3);
    const bf16_t* bP0 = Bmat + (size_t)(v0 + row0) * Hd + (sub0 << 3);
    const bf16_t* bP1 = Bmat + (size_t)(v0 + row1) * Hd + (sub1 << 3);

    uint4 pa0 = *(const uint4*)(aP0), pa1 = *(const uint4*)(aP1);
    uint4 pb0 = *(const uint4*)(bP0), pb1 = *(const uint4*)(bP1);

    for (int kb = 0; kb < 16; ++kb) {
        __syncthreads();
        *(uint4*)(At + row0 * 32 + (sw0 << 3)) = pa0;
        *(uint4*)(At + row1 * 32 + (sw1 << 3)) = pa1;
        *(uint4*)(Bt + row0 * 32 + (sw0 << 3)) = pb0;
        *(uint4*)(Bt + row1 * 32 + (sw1 << 3)) = pb1;
        __syncthreads();
        if (kb < 15) {
            int ko = (kb + 1) << 5;
            pa0 = *(const uint4*)(aP0 + ko); pa1 = *(const uint4*)(aP1 + ko);
            pb0 = *(const uint4*)(bP0 + ko); pb1 = *(const uint4*)(bP1 + ko);
        }
        bf16x8 af[4], bfr[4];
        #pragma unroll
        for (int mi = 0; mi < 4; ++mi) {
            int m = moff + (mi << 4) + l15;
            af[mi] = *(const bf16x8*)(At + m * 32 + (((q8 ^ (m & 3)) & 3) << 3));
        }
        #pragma unroll
        for (int vi = 0; vi < 4; ++vi) {
            int vv = voff + (vi << 4) + l15;
            bfr[vi] = *(const bf16x8*)(Bt + vv * 32 + (((q8 ^ (vv & 3)) & 3) << 3));
        }
        #pragma unroll
        for (int mi = 0; mi < 4; ++mi)
            #pragma unroll
            for (int vi = 0; vi < 4; ++vi)
                acc[mi][vi] = __builtin_amdgcn_mfma_f32_16x16x32_bf16(af[mi], bfr[vi], acc[mi][vi], 0, 0, 0);
    }

    float bz[4];
    #pragma unroll
    for (int vi = 0; vi < 4; ++vi) bz[vi] = bias[v0 + voff + (vi << 4) + l15];

    float rm[16], rl[16];
    #pragma unroll
    for (int k = 0; k < 16; ++k) rm[k] = -3.4e38f;
    #pragma unroll
    for (int mi = 0; mi < 4; ++mi)
        #pragma unroll
        for (int r = 0; r < 4; ++r)
            #pragma unroll
            for (int vi = 0; vi < 4; ++vi)
                rm[mi * 4 + r] = fmaxf(rm[mi * 4 + r], acc[mi][vi][r] + bz[vi]);
    #pragma unroll
    for (int mask = 1; mask < 16; mask <<= 1)
        #pragma unroll
        for (int k = 0; k < 16; ++k)
            rm[k] = fmaxf(rm[k], __shfl_xor(rm[k], mask, 64));
    #pragma unroll
    for (int k = 0; k < 16; ++k) rl[k] = 0.f;
    #pragma unroll
    for (int vi = 0; vi < 4; ++vi) {
        int col = v0 + voff + (vi << 4) + l15;
        #pragma unroll
        for (int mi = 0; mi < 4; ++mi) {
            int row = n0 + moff + (mi << 4) + (q8 << 2);
            #pragma unroll
            for (int r = 0; r < 4; ++r) {
                float z = acc[mi][vi][r] + bz[vi];
                out[(size_t)(row + r) * Vd + col] = z;
                rl[mi * 4 + r] += __expf(z - rm[mi * 4 + r]);
            }
        }
    }
    #pragma unroll
    for (int mask = 1; mask < 16; mask <<= 1)
        #pragma unroll
        for (int k = 0; k < 16; ++k)
            rl[k] += __shfl_xor(rl[k], mask, 64);

    if (l15 == 0) {
        int half = w >> 1;
        #pragma unroll
        for (int mi = 0; mi < 4; ++mi)
            #pragma unroll
            for (int r = 0; r < 4; ++r) {
                int rloc = moff + (mi << 4) + (q8 << 2) + r;
                smM[rloc][half] = rm[mi * 4 + r];
                smL[rloc][half] = rl[mi * 4 + r];
            }
    }
    __syncthreads();
    if (tid < 128) {
        float m0 = smM[tid][0], m1 = smM[tid][1];
        float l0 = smL[tid][0], l1 = smL[tid][1];
        float M = fmaxf(m0, m1);
        float L = l0 * __expf(m0 - M) + l1 * __expf(m1 - M);
        part2[(size_t)(n0 + tid) * 250 + yv] = make_float2(M, L);
    }
}

// ---------------------------------------------------------------------------
// K4: fused logZ + subtract. One block per row: combine 250 partials
// (contiguous 2 KB), then one read+write pass over the row.
// ---------------------------------------------------------------------------
__global__ void k_lsub(float* __restrict__ out, const float2* __restrict__ part2)
{
    const int n = blockIdx.x, tid = threadIdx.x;
    __shared__ float smx[256], sl[256];
    float m = -3.4e38f, l = 0.f;
    if (tid < 250) {
        float2 pp = part2[(size_t)n * 250 + tid];
        m = pp.x; l = pp.y;
    }
    smx[tid] = m; sl[tid] = l;
    __syncthreads();
    for (int s2 = 128; s2 > 0; s2 >>= 1) {
        if (tid < s2) {
            float m1 = smx[tid], l1 = sl[tid];
            float m2 = smx[tid + s2], l2 = sl[tid + s2];
            float nm = fmaxf(m1, m2);
            sl[tid] = l1 * __expf(m1 - nm) + l2 * __expf(m2 - nm);
            smx[tid] = nm;
        }
        __syncthreads();
    }
    const float z = smx[0] + __logf(sl[0]);
    float4* row = (float4*)(out + (size_t)n * Vd);
    #pragma unroll 4
    for (int i = 0; i < 31; ++i) {             // 31*256 = 7936 of 8000 float4
        int idx = i * 256 + tid;
        float4 x = row[idx];
        x.x -= z; x.y -= z; x.z -= z; x.w -= z;
        row[idx] = x;
    }
    if (tid < 64) {                            // tail 64 float4
        int idx = 7936 + tid;
        float4 x = row[idx];
        x.x -= z; x.y -= z; x.z -= z; x.w -= z;
        row[idx] = x;
    }
}

// ---------------------------------------------------------------------------
extern "C" void kernel_launch(void* const* d_in, const int* in_sizes, int n_in,
                              void* d_out, int out_size, void* d_ws, size_t ws_size,
                              hipStream_t stream)
{
    const int*   src       = (const int*)d_in[0];
    const int*   tgt       = (const int*)d_in[1];
    const float* enc_embed = (const float*)d_in[2];
    const float* enc_wih   = (const float*)d_in[3];
    const float* enc_bih   = (const float*)d_in[4];
    const float* enc_whh   = (const float*)d_in[5];
    const float* enc_bhh   = (const float*)d_in[6];
    const float* dec_embed = (const float*)d_in[7];
    const float* dec_wih   = (const float*)d_in[8];
    const float* dec_bih   = (const float*)d_in[9];
    const float* dec_whh   = (const float*)d_in[10];
    const float* dec_bhh   = (const float*)d_in[11];
    const float* h2o_w     = (const float*)d_in[12];
    const float* h2o_b     = (const float*)d_in[13];
    float* out = (float*)d_out;

    char* ws = (char*)d_ws;
    float*  Aenc  = (float*)(ws);                        // 4 MB (dead after k_rec)
    float*  Adec  = (float*)(ws + ((size_t)4 << 20));    // 4 MB
    unsigned long long* encX = (unsigned long long*)(ws + ((size_t)8 << 20));               // 256 KB
    unsigned long long* decX = (unsigned long long*)(ws + ((size_t)8 << 20) + (256 << 10)); // 256 KB
    bf16_t* dhsB  = (bf16_t*)(ws + ((size_t)9 << 20));   // 2 MB
    bf16_t* wT    = (bf16_t*)(ws + ((size_t)12 << 20));  // 31.25 MB
    float2* part2 = (float2*)(ws);                       // 4 MB, reuses Aenc (dead)

    k_prep<<<4256, 256, 0, stream>>>(src, tgt,
        enc_embed, enc_wih, enc_bih, enc_bhh,
        dec_embed, dec_wih, dec_bih, dec_bhh, Aenc, Adec,
        h2o_w, wT, encX, decX);
    k_rec<<<256, 256, 0, stream>>>(enc_whh, dec_whh, Aenc, Adec,
        encX, decX, dhsB);
    k_gemm<<<4000, 256, 0, stream>>>(dhsB, wT, h2o_b, out, part2);
    k_lsub<<<2048, 256, 0, stream>>>(out, part2);
}